// Round 13
// baseline (129.030 us; speedup 1.0000x reference)
//
#include <hip/hip_runtime.h>
#include <hip/hip_fp16.h>

// DRR ray-casting for MI355X — round 13.
// r12: main restructure (fine-grain tile x k-quarter + atomic partials) WORKED
// (63 -> 50.4 us, occ 50%, VALU 40%) but total regressed 95 -> 128 because the
// pack kernel ballooned ~28 -> ~45+ us. Suspect: cvt_pkrtz + bit_cast forcing
// a scratch round-trip (rule #20). r13 = r12 with pack reverted to the
// r10-proven __halves2half2 body. Main/minmax/norm unchanged.

static __device__ __constant__ float kPX     = 1.6875f;
static __device__ __constant__ float kPIERCE = 216.0f;
static __device__ __constant__ float kSAD    = 742.5f;
static __device__ __constant__ float kDAD    = 517.15f;

#define VOL_BYTES   (256u * 256u * 256u * 4u)
#define PAIR_R      258u
#define PAIR_ELEMS  (256u * 256u * PAIR_R)          // half2 elements
#define PAIR_BYTES  (PAIR_ELEMS * 4u)

__global__ void drr_init_mm(unsigned* mm) {
    int i = threadIdx.x;
    if (i < 4) mm[i] = (i & 1) ? 0u : 0x7F800000u;  // max<-0, min<-+inf
}

// ---------------- pack: vol[x][y][z] -> vhp[z][y][i] = (v[i-1], v[i]) fp16 ---
// r10-proven body (__halves2half2). Also zeroes raw (32 px/block, needed for
// the atomic partial sums) and inits mm (block 0).
__global__ __launch_bounds__(256) void drr_pack(const float* __restrict__ vol,
                                                __half2* __restrict__ vhp,
                                                float* __restrict__ raw,
                                                unsigned* __restrict__ mm) {
    const int bid = blockIdx.x;
    if (bid == 0 && threadIdx.x < 4)
        mm[threadIdx.x] = (threadIdx.x & 1) ? 0u : 0x7F800000u;
    if (threadIdx.x < 32)
        raw[(bid << 5) + threadIdx.x] = 0.0f;

    __shared__ float tile[65][65];
    const int y    = bid >> 4;
    const int t4   = bid & 15;
    const int x0   = (t4 & 3) << 6;
    const int z0   = (t4 >> 2) << 6;

    const int rr = threadIdx.x >> 4;   // 0..15 row within pass
    const int cc = threadIdx.x & 15;   // 0..15 float4 column
    #pragma unroll
    for (int base = 0; base < 80; base += 16) {
        const int r = base + rr;
        if (r < 65) {
            const int x = x0 - 1 + r;
            float4 f = make_float4(0.0f, 0.0f, 0.0f, 0.0f);
            if (x >= 0)
                f = *(const float4*)&vol[(x << 16) | (y << 8) | (z0 + (cc << 2))];
            tile[r][(cc << 2) + 0] = f.x;
            tile[r][(cc << 2) + 1] = f.y;
            tile[r][(cc << 2) + 2] = f.z;
            tile[r][(cc << 2) + 3] = f.w;
        }
    }
    __syncthreads();

    const int lane = threadIdx.x & 63;
    const int row4 = threadIdx.x >> 6;  // 0..3
    for (int r = row4; r < 64; r += 4) {
        const int z = z0 + r;
        const unsigned base = (unsigned)((z << 8) | y) * PAIR_R;
        vhp[base + x0 + lane] =
            __halves2half2(__float2half(tile[lane][r]), __float2half(tile[lane + 1][r]));
    }
    if ((t4 & 3) == 3) {
        for (int r = row4; r < 64; r += 4) {
            const int z = z0 + r;
            const unsigned base = (unsigned)((z << 8) | y) * PAIR_R;
            if (lane == 0) {
                vhp[base + 256] = __halves2half2(__float2half(tile[64][r]), __float2half(0.0f));
                vhp[base + 257] = __halves2half2(__float2half(0.0f), __float2half(0.0f));
            }
        }
    }
}

// Per-dimension slab: tighten [tlo, thi] to where s + t*r is in [lo, hi].
__device__ __forceinline__ void slab(float s, float r, float lo, float hi,
                                     float& tlo, float& thi) {
    if (fabsf(r) > 1e-8f) {
        const float inv = 1.0f / r;
        const float ta  = (lo - s) * inv;
        const float tb  = (hi - s) * inv;
        tlo = fmaxf(tlo, fminf(ta, tb));
        thi = fminf(thi, fmaxf(ta, tb));
    } else if (s < lo || s > hi) {
        tlo = 2.0f; thi = -1.0f;  // empty
    }
}

struct RayCfg {
    float rx, ry, rz, length;
    int k_lo, k_hi;   // loose window (outside: exactly zero via masks)
    int s_lo, s_hi;   // strict window (inside: all masks 1, no clamps)
};

__device__ __forceinline__ void cfg_windows(float sx, float sy, float sz, RayCfg& c) {
    float tlo = 0.0f, thi = 1.0f;
    slab(sx, c.rx, -1.02f, 256.02f, tlo, thi);
    slab(sy, c.ry, -1.02f, 256.02f, tlo, thi);
    slab(sz, c.rz, -1.02f, 256.02f, tlo, thi);
    c.k_lo = 0; c.k_hi = -1;
    if (thi >= tlo) {
        c.k_lo = max(0,   (int)ceilf(tlo * 255.0f - 1e-3f));
        c.k_hi = min(255, (int)floorf(thi * 255.0f + 1e-3f));
    }
    float slo = 0.0f, shi = 1.0f;
    slab(sx, c.rx, 0.01f, 254.99f, slo, shi);
    slab(sy, c.ry, 0.01f, 254.99f, slo, shi);
    slab(sz, c.rz, 0.01f, 254.99f, slo, shi);
    c.s_lo = 1; c.s_hi = -1;
    if (shi >= slo) {
        c.s_lo = (int)ceilf(slo * 255.0f + 1e-3f);
        c.s_hi = (int)floorf(shi * 255.0f - 1e-3f);
    }
}

// Shared pose math; A = pixel (u, v0), B = pixel (u, v0+1).
__device__ __forceinline__ void ray_setup2(const float* __restrict__ batch,
                                           int b, int u, int v0,
                                           float& sx, float& sy, float& sz,
                                           RayCfg& A, RayCfg& B) {
    const float a  = batch[b * 6 + 0];
    const float be = batch[b * 6 + 1];
    const float g  = batch[b * 6 + 2];
    const float tx = batch[b * 6 + 3];
    const float ty = batch[b * 6 + 4];
    const float tz = batch[b * 6 + 5];

    float sa, ca, sb, cb, sg, cg;
    sincosf(a, &sa, &ca);
    sincosf(be, &sb, &cb);
    sincosf(g, &sg, &cg);

    const float R00 = ca * cb;
    const float R01 = ca * sb * sg - sa * cg;
    const float R02 = sa * sg + ca * sb * cg;
    const float R10 = sa * cb;
    const float R11 = ca * cg + sa * sb * sg;
    const float R12 = sa * sb * cg - ca * sg;
    const float R20 = -sb;
    const float R21 = cb * sg;
    const float R22 = cb * cg;

    sx = 128.0f + tx + kSAD * R02;
    sy = 128.0f + ty + kSAD * R12;
    sz = 128.0f + tz + kSAD * R22;

    const float uu = u * kPX - kPIERCE;
    const float vv = v0 * kPX - kPIERCE;
    A.rx = uu * R00 + vv * R01 - (kSAD + kDAD) * R02;
    A.ry = uu * R10 + vv * R11 - (kSAD + kDAD) * R12;
    A.rz = uu * R20 + vv * R21 - (kSAD + kDAD) * R22;
    B.rx = A.rx + kPX * R01;
    B.ry = A.ry + kPX * R11;
    B.rz = A.rz + kPX * R21;
    A.length = sqrtf(A.rx * A.rx + A.ry * A.ry + A.rz * A.rz);
    B.length = sqrtf(B.rx * B.rx + B.ry * B.ry + B.rz * B.rz);
    cfg_windows(sx, sy, sz, A);
    cfg_windows(sx, sy, sz, B);
}

// Interior sample: all 8 corners in-bounds, no masks/clamps (bit-exact when
// the strict window guarantee holds).
__device__ __forceinline__ float tri_fast(const __half2* __restrict__ vhp,
                                          float sx, float sy, float sz,
                                          const RayCfg& c, float t) {
    const float px = fmaf(t, c.rx, sx);
    const float py = fmaf(t, c.ry, sy);
    const float pz = fmaf(t, c.rz, sz);
    const float fx = floorf(px), fy = floorf(py), fz = floorf(pz);
    const int ix = (int)fx, iy = (int)fy, iz = (int)fz;
    const float wx = px - fx, wy = py - fy, wz = pz - fz;

    const unsigned base = (unsigned)iz * 66048u + (unsigned)iy * 258u + (unsigned)(ix + 1);
    const __half2 q00 = vhp[base];
    const __half2 q01 = vhp[base + 66048u];
    const __half2 q10 = vhp[base + 258u];
    const __half2 q11 = vhp[base + 66306u];

    const float wx0 = 1.0f - wx, wy0 = 1.0f - wy, wz0 = 1.0f - wz;
    const float a00 = __low2float(q00) * wx0 + __high2float(q00) * wx;
    const float a01 = __low2float(q01) * wx0 + __high2float(q01) * wx;
    const float a10 = __low2float(q10) * wx0 + __high2float(q10) * wx;
    const float a11 = __low2float(q11) * wx0 + __high2float(q11) * wx;
    return (a00 * wz0 + a01 * wz) * wy0 + (a10 * wz0 + a11 * wz) * wy;
}

// Boundary sample: masks folded into weights, clamped addresses.
__device__ __forceinline__ float tri_slow(const __half2* __restrict__ vhp,
                                          float sx, float sy, float sz,
                                          const RayCfg& c, float t) {
    const float px = fmaf(t, c.rx, sx);
    const float py = fmaf(t, c.ry, sy);
    const float pz = fmaf(t, c.rz, sz);
    const float fx = floorf(px), fy = floorf(py), fz = floorf(pz);
    const int ix = (int)fx, iy = (int)fy, iz = (int)fz;
    const float wx = px - fx, wy = py - fy, wz = pz - fz;

    const float mx0 = ((unsigned)ix       < 256u) ? 1.0f : 0.0f;
    const float mx1 = ((unsigned)(ix + 1) < 256u) ? 1.0f : 0.0f;
    const float my0 = ((unsigned)iy       < 256u) ? 1.0f : 0.0f;
    const float my1 = ((unsigned)(iy + 1) < 256u) ? 1.0f : 0.0f;
    const float mz0 = ((unsigned)iz       < 256u) ? 1.0f : 0.0f;
    const float mz1 = ((unsigned)(iz + 1) < 256u) ? 1.0f : 0.0f;

    const int i  = min(max(ix + 1, 0), 257);
    const int y0 = min(max(iy,     0), 255);
    const int y1 = min(max(iy + 1, 0), 255);
    const int z0 = min(max(iz,     0), 255);
    const int z1 = min(max(iz + 1, 0), 255);

    const unsigned zt0 = (unsigned)z0 * 66048u;
    const unsigned zt1 = (unsigned)z1 * 66048u;
    const unsigned yt0 = (unsigned)y0 * 258u;
    const unsigned yt1 = (unsigned)y1 * 258u;

    const __half2 q00 = vhp[zt0 + yt0 + i];
    const __half2 q01 = vhp[zt1 + yt0 + i];
    const __half2 q10 = vhp[zt0 + yt1 + i];
    const __half2 q11 = vhp[zt1 + yt1 + i];

    const float wx0 = (1.0f - wx) * mx0, wx1 = wx * mx1;
    const float wy0 = (1.0f - wy) * my0, wy1 = wy * my1;
    const float wz0 = (1.0f - wz) * mz0, wz1 = wz * mz1;

    const float a00 = __low2float(q00) * wx0 + __high2float(q00) * wx1;
    const float a01 = __low2float(q01) * wx0 + __high2float(q01) * wx1;
    const float a10 = __low2float(q10) * wx0 + __high2float(q10) * wx1;
    const float a11 = __low2float(q11) * wx0 + __high2float(q11) * wx1;
    return (a00 * wz0 + a01 * wz1) * wy0 + (a10 * wz0 + a11 * wz1) * wy1;
}

// Grid = 4096 blocks = (1024 tiles) x (4 k-quarters). Block = 256 thr = 4
// waves. Tile = 16u x 8v, 2 v-adjacent px per lane. Lane's k residues:
// kq*4 + seg (mod 16). Partial pixel sums (pre-scaled) atomicAdd'ed into raw.
__global__ __launch_bounds__(256, 8) void drr_main_pk3(const __half2* __restrict__ vhp,
                                                       const float* __restrict__ batch,
                                                       float* __restrict__ raw) {
    const int tid  = threadIdx.x;
    const int lane = tid & 63;
    const int seg  = tid >> 6;            // 0..3

    const int kq   = blockIdx.x & 3;      // k-quarter
    const int tile = blockIdx.x >> 2;     // 0..1023
    const int b    = tile >> 9;
    const int ti   = tile & 511;
    const int u    = ((ti & 15) << 4) + (lane & 15);
    const int v0   = ((ti >> 4) << 3) + ((lane >> 4) << 1);

    float sx, sy, sz;
    RayCfg A, B;
    ray_setup2(batch, b, u, v0, sx, sy, sz, A, B);

    const int klo = min(A.k_lo, B.k_lo);
    const int khi = max(A.k_hi, B.k_hi);
    const int slo = max(A.s_lo, B.s_lo);
    const int shi = min(A.s_hi, B.s_hi);

    const float tstep = 1.0f / 255.0f;
    float sA = 0.0f, sB = 0.0f;
    for (int k = klo + (kq << 2) + seg; k <= khi; k += 16) {
        const float t = (float)k * tstep;
        if (k >= slo && k <= shi) {
            sA += tri_fast(vhp, sx, sy, sz, A, t);
            sB += tri_fast(vhp, sx, sy, sz, B, t);
        } else {
            sA += tri_slow(vhp, sx, sy, sz, A, t);
            sB += tri_slow(vhp, sx, sy, sz, B, t);
        }
    }

    __shared__ float pA[4][64], pB[4][64];
    pA[seg][lane] = sA;
    pB[seg][lane] = sB;
    __syncthreads();

    if (tid < 64) {
        const float tA = pA[0][lane] + pA[1][lane] + pA[2][lane] + pA[3][lane];
        const float tB = pB[0][lane] + pB[1][lane] + pB[2][lane] + pB[3][lane];
        if (tA != 0.0f)
            atomicAdd(&raw[(b << 16) + (v0 << 8) + u],       tA * (A.length * (1.0f / 256.0f)));
        if (tB != 0.0f)
            atomicAdd(&raw[(b << 16) + ((v0 + 1) << 8) + u], tB * (B.length * (1.0f / 256.0f)));
    }
}

// Min/max over each image (raw values >= 0 -> uint ordering).
__global__ __launch_bounds__(256) void drr_minmax(const float* __restrict__ raw,
                                                  unsigned* __restrict__ mm) {
    const int gid = blockIdx.x * 256 + threadIdx.x;
    const int b   = gid >> 16;
    const float x = raw[gid];
    float mn = x, mx = x;
    #pragma unroll
    for (int off = 32; off >= 1; off >>= 1) {
        mn = fminf(mn, __shfl_xor(mn, off));
        mx = fmaxf(mx, __shfl_xor(mx, off));
    }
    if ((threadIdx.x & 63) == 0) {
        atomicMin(&mm[2 * b + 0], __float_as_uint(mn));
        atomicMax(&mm[2 * b + 1], __float_as_uint(mx));
    }
}

__global__ __launch_bounds__(256) void drr_norm(float* __restrict__ img,
                                                const unsigned* __restrict__ mm) {
    const int gid = blockIdx.x * 256 + threadIdx.x;
    const int b   = gid >> 16;
    const float mn  = __uint_as_float(mm[2 * b + 0]);
    const float mx  = __uint_as_float(mm[2 * b + 1]);
    const float inv = 1.0f / (mx - mn);
    img[gid] = 1.0f - (img[gid] - mn) * inv;
}

// ---------------- fallback (ws too small for pair array): f32 path ---------
__global__ __launch_bounds__(256) void drr_transpose(const float* __restrict__ vol,
                                                     float* __restrict__ volt) {
    __shared__ float tile[64][65];
    const int bid  = blockIdx.x;
    const int y    = bid >> 4;
    const int t4   = bid & 15;
    const int x0   = (t4 & 3) << 6;
    const int z0   = (t4 >> 2) << 6;
    const int lane = threadIdx.x & 63;
    const int row4 = threadIdx.x >> 6;

    #pragma unroll
    for (int i = 0; i < 16; ++i) {
        const int xr = (i << 2) + row4;
        tile[xr][lane] = vol[((x0 + xr) << 16) | (y << 8) | (z0 + lane)];
    }
    __syncthreads();
    #pragma unroll
    for (int i = 0; i < 16; ++i) {
        const int zr = (i << 2) + row4;
        volt[((z0 + zr) << 16) | (y << 8) | (x0 + lane)] = tile[lane][zr];
    }
}

__device__ __forceinline__ float tri_sample_f32(const float* __restrict__ vol,
                                                float sx, float sy, float sz,
                                                const RayCfg& c, float t) {
    const float px = fmaf(t, c.rx, sx);
    const float py = fmaf(t, c.ry, sy);
    const float pz = fmaf(t, c.rz, sz);
    const float fx = floorf(px), fy = floorf(py), fz = floorf(pz);
    const int ix = (int)fx, iy = (int)fy, iz = (int)fz;
    const float wx = px - fx, wy = py - fy, wz = pz - fz;
    const float mx0 = ((unsigned)ix       < 256u) ? 1.0f : 0.0f;
    const float mx1 = ((unsigned)(ix + 1) < 256u) ? 1.0f : 0.0f;
    const float my0 = ((unsigned)iy       < 256u) ? 1.0f : 0.0f;
    const float my1 = ((unsigned)(iy + 1) < 256u) ? 1.0f : 0.0f;
    const float mz0 = ((unsigned)iz       < 256u) ? 1.0f : 0.0f;
    const float mz1 = ((unsigned)(iz + 1) < 256u) ? 1.0f : 0.0f;
    const unsigned X0 = (unsigned)ix & 255u, X1 = (unsigned)(ix + 1) & 255u;
    const unsigned Y0 = ((unsigned)iy & 255u) << 8, Y1 = ((unsigned)(iy + 1) & 255u) << 8;
    const unsigned Z0 = ((unsigned)iz & 255u) << 16, Z1 = ((unsigned)(iz + 1) & 255u) << 16;
    const float v000 = vol[Z0 | Y0 | X0];
    const float v001 = vol[Z1 | Y0 | X0];
    const float v010 = vol[Z0 | Y1 | X0];
    const float v011 = vol[Z1 | Y1 | X0];
    const float v100 = vol[Z0 | Y0 | X1];
    const float v101 = vol[Z1 | Y0 | X1];
    const float v110 = vol[Z0 | Y1 | X1];
    const float v111 = vol[Z1 | Y1 | X1];
    const float wx0 = (1.0f - wx) * mx0, wx1 = wx * mx1;
    const float wy0 = (1.0f - wy) * my0, wy1 = wy * my1;
    const float wz0 = (1.0f - wz) * mz0, wz1 = wz * mz1;
    const float c00 = v000 * wz0 + v001 * wz1;
    const float c01 = v010 * wz0 + v011 * wz1;
    const float c10 = v100 * wz0 + v101 * wz1;
    const float c11 = v110 * wz0 + v111 * wz1;
    return (c00 * wy0 + c01 * wy1) * wx0 + (c10 * wy0 + c11 * wy1) * wx1;
}

__global__ __launch_bounds__(256, 4) void drr_main_f32(const float* __restrict__ volt,
                                                       const float* __restrict__ batch,
                                                       float* __restrict__ raw,
                                                       unsigned* __restrict__ mm) {
    const int tid  = threadIdx.x;
    const int lane = tid & 63;
    const int seg  = tid >> 6;
    const int tile = blockIdx.x;
    const int b    = tile >> 10;
    const int ti   = tile & 1023;
    const int u    = ((ti & 15) << 4) + (lane & 15);
    const int v    = ((ti >> 4) << 2) + (lane >> 4);

    float sx, sy, sz;
    RayCfg A, B;
    ray_setup2(batch, b, u, v, sx, sy, sz, A, B);  // use A only

    const float tstep = 1.0f / 255.0f;
    float sum = 0.0f;
    for (int k = A.k_lo + seg; k <= A.k_hi; k += 4)
        sum += tri_sample_f32(volt, sx, sy, sz, A, (float)k * tstep);

    __shared__ float part[4][64];
    part[seg][lane] = sum;
    __syncthreads();

    if (tid < 64) {
        const float s = part[0][lane] + part[1][lane] + part[2][lane] + part[3][lane];
        const float rawv = s * (A.length * (1.0f / 256.0f));
        raw[(b << 16) + (v << 8) + u] = rawv;
        float mn = rawv, mx = rawv;
        #pragma unroll
        for (int off = 32; off >= 1; off >>= 1) {
            mn = fminf(mn, __shfl_xor(mn, off));
            mx = fmaxf(mx, __shfl_xor(mx, off));
        }
        if (lane == 0) {
            atomicMin(&mm[2 * b + 0], __float_as_uint(mn));
            atomicMax(&mm[2 * b + 1], __float_as_uint(mx));
        }
    }
}

extern "C" void kernel_launch(void* const* d_in, const int* in_sizes, int n_in,
                              void* d_out, int out_size, void* d_ws, size_t ws_size,
                              hipStream_t stream) {
    const float* vol   = (const float*)d_in[0];
    const float* batch = (const float*)d_in[1];
    float* out         = (float*)d_out;

    if (ws_size >= (size_t)PAIR_BYTES + 16) {
        __half2*  vhp = (__half2*)d_ws;
        unsigned* mm  = (unsigned*)((char*)d_ws + PAIR_BYTES);
        drr_pack<<<4096, 256, 0, stream>>>(vol, vhp, out, mm);
        drr_main_pk3<<<4096, 256, 0, stream>>>(vhp, batch, out);
        drr_minmax<<<512, 256, 0, stream>>>(out, mm);
        drr_norm<<<512, 256, 0, stream>>>(out, mm);
    } else {
        float*    volt = (float*)d_ws;
        unsigned* mm   = (unsigned*)((char*)d_ws + VOL_BYTES);
        drr_init_mm<<<1, 64, 0, stream>>>(mm);
        drr_transpose<<<4096, 256, 0, stream>>>(vol, volt);
        drr_main_f32<<<2048, 256, 0, stream>>>(volt, batch, out, mm);
        drr_norm<<<512, 256, 0, stream>>>(out, mm);
    }
}

// Round 14
// 83.228 us; speedup vs baseline: 1.5503x; 1.5503x over previous
//
#include <hip/hip_runtime.h>
#include <hip/hip_fp16.h>

// DRR ray-casting for MI355X — round 14.
// r13 refuted the pack theory (revert changed nothing). Re-accounting: the
// ~43 us thief is drr_minmax's 4096 same-address atomics (4 addresses),
// exposed standalone (in r1-r10 they were hidden in main's 50-65 us epilogue
// as blocks retired; standalone they serialize at ~10-20 ns each).
// r14: minmax -> per-block reduce + PLAIN partial stores (no atomics);
// norm -> re-reduce the 256 partial pairs per image in-block, then normalize.
// pack/main_pk3 byte-identical to r13 (main proven 50.4 us).

static __device__ __constant__ float kPX     = 1.6875f;
static __device__ __constant__ float kPIERCE = 216.0f;
static __device__ __constant__ float kSAD    = 742.5f;
static __device__ __constant__ float kDAD    = 517.15f;

#define VOL_BYTES   (256u * 256u * 256u * 4u)
#define PAIR_R      258u
#define PAIR_ELEMS  (256u * 256u * PAIR_R)          // half2 elements
#define PAIR_BYTES  (PAIR_ELEMS * 4u)

__global__ void drr_init_mm(unsigned* mm) {
    int i = threadIdx.x;
    if (i < 4) mm[i] = (i & 1) ? 0u : 0x7F800000u;  // max<-0, min<-+inf
}

// ---------------- pack: vol[x][y][z] -> vhp[z][y][i] = (v[i-1], v[i]) fp16 ---
// r10-proven body. Also zeroes raw (for main's atomic partial sums).
__global__ __launch_bounds__(256) void drr_pack(const float* __restrict__ vol,
                                                __half2* __restrict__ vhp,
                                                float* __restrict__ raw) {
    const int bid = blockIdx.x;
    if (threadIdx.x < 32)
        raw[(bid << 5) + threadIdx.x] = 0.0f;

    __shared__ float tile[65][65];
    const int y    = bid >> 4;
    const int t4   = bid & 15;
    const int x0   = (t4 & 3) << 6;
    const int z0   = (t4 >> 2) << 6;

    const int rr = threadIdx.x >> 4;   // 0..15 row within pass
    const int cc = threadIdx.x & 15;   // 0..15 float4 column
    #pragma unroll
    for (int base = 0; base < 80; base += 16) {
        const int r = base + rr;
        if (r < 65) {
            const int x = x0 - 1 + r;
            float4 f = make_float4(0.0f, 0.0f, 0.0f, 0.0f);
            if (x >= 0)
                f = *(const float4*)&vol[(x << 16) | (y << 8) | (z0 + (cc << 2))];
            tile[r][(cc << 2) + 0] = f.x;
            tile[r][(cc << 2) + 1] = f.y;
            tile[r][(cc << 2) + 2] = f.z;
            tile[r][(cc << 2) + 3] = f.w;
        }
    }
    __syncthreads();

    const int lane = threadIdx.x & 63;
    const int row4 = threadIdx.x >> 6;  // 0..3
    for (int r = row4; r < 64; r += 4) {
        const int z = z0 + r;
        const unsigned base = (unsigned)((z << 8) | y) * PAIR_R;
        vhp[base + x0 + lane] =
            __halves2half2(__float2half(tile[lane][r]), __float2half(tile[lane + 1][r]));
    }
    if ((t4 & 3) == 3) {
        for (int r = row4; r < 64; r += 4) {
            const int z = z0 + r;
            const unsigned base = (unsigned)((z << 8) | y) * PAIR_R;
            if (lane == 0) {
                vhp[base + 256] = __halves2half2(__float2half(tile[64][r]), __float2half(0.0f));
                vhp[base + 257] = __halves2half2(__float2half(0.0f), __float2half(0.0f));
            }
        }
    }
}

// Per-dimension slab: tighten [tlo, thi] to where s + t*r is in [lo, hi].
__device__ __forceinline__ void slab(float s, float r, float lo, float hi,
                                     float& tlo, float& thi) {
    if (fabsf(r) > 1e-8f) {
        const float inv = 1.0f / r;
        const float ta  = (lo - s) * inv;
        const float tb  = (hi - s) * inv;
        tlo = fmaxf(tlo, fminf(ta, tb));
        thi = fminf(thi, fmaxf(ta, tb));
    } else if (s < lo || s > hi) {
        tlo = 2.0f; thi = -1.0f;  // empty
    }
}

struct RayCfg {
    float rx, ry, rz, length;
    int k_lo, k_hi;   // loose window (outside: exactly zero via masks)
    int s_lo, s_hi;   // strict window (inside: all masks 1, no clamps)
};

__device__ __forceinline__ void cfg_windows(float sx, float sy, float sz, RayCfg& c) {
    float tlo = 0.0f, thi = 1.0f;
    slab(sx, c.rx, -1.02f, 256.02f, tlo, thi);
    slab(sy, c.ry, -1.02f, 256.02f, tlo, thi);
    slab(sz, c.rz, -1.02f, 256.02f, tlo, thi);
    c.k_lo = 0; c.k_hi = -1;
    if (thi >= tlo) {
        c.k_lo = max(0,   (int)ceilf(tlo * 255.0f - 1e-3f));
        c.k_hi = min(255, (int)floorf(thi * 255.0f + 1e-3f));
    }
    float slo = 0.0f, shi = 1.0f;
    slab(sx, c.rx, 0.01f, 254.99f, slo, shi);
    slab(sy, c.ry, 0.01f, 254.99f, slo, shi);
    slab(sz, c.rz, 0.01f, 254.99f, slo, shi);
    c.s_lo = 1; c.s_hi = -1;
    if (shi >= slo) {
        c.s_lo = (int)ceilf(slo * 255.0f + 1e-3f);
        c.s_hi = (int)floorf(shi * 255.0f - 1e-3f);
    }
}

// Shared pose math; A = pixel (u, v0), B = pixel (u, v0+1).
__device__ __forceinline__ void ray_setup2(const float* __restrict__ batch,
                                           int b, int u, int v0,
                                           float& sx, float& sy, float& sz,
                                           RayCfg& A, RayCfg& B) {
    const float a  = batch[b * 6 + 0];
    const float be = batch[b * 6 + 1];
    const float g  = batch[b * 6 + 2];
    const float tx = batch[b * 6 + 3];
    const float ty = batch[b * 6 + 4];
    const float tz = batch[b * 6 + 5];

    float sa, ca, sb, cb, sg, cg;
    sincosf(a, &sa, &ca);
    sincosf(be, &sb, &cb);
    sincosf(g, &sg, &cg);

    const float R00 = ca * cb;
    const float R01 = ca * sb * sg - sa * cg;
    const float R02 = sa * sg + ca * sb * cg;
    const float R10 = sa * cb;
    const float R11 = ca * cg + sa * sb * sg;
    const float R12 = sa * sb * cg - ca * sg;
    const float R20 = -sb;
    const float R21 = cb * sg;
    const float R22 = cb * cg;

    sx = 128.0f + tx + kSAD * R02;
    sy = 128.0f + ty + kSAD * R12;
    sz = 128.0f + tz + kSAD * R22;

    const float uu = u * kPX - kPIERCE;
    const float vv = v0 * kPX - kPIERCE;
    A.rx = uu * R00 + vv * R01 - (kSAD + kDAD) * R02;
    A.ry = uu * R10 + vv * R11 - (kSAD + kDAD) * R12;
    A.rz = uu * R20 + vv * R21 - (kSAD + kDAD) * R22;
    B.rx = A.rx + kPX * R01;
    B.ry = A.ry + kPX * R11;
    B.rz = A.rz + kPX * R21;
    A.length = sqrtf(A.rx * A.rx + A.ry * A.ry + A.rz * A.rz);
    B.length = sqrtf(B.rx * B.rx + B.ry * B.ry + B.rz * B.rz);
    cfg_windows(sx, sy, sz, A);
    cfg_windows(sx, sy, sz, B);
}

// Interior sample: all 8 corners in-bounds, no masks/clamps (bit-exact when
// the strict window guarantee holds).
__device__ __forceinline__ float tri_fast(const __half2* __restrict__ vhp,
                                          float sx, float sy, float sz,
                                          const RayCfg& c, float t) {
    const float px = fmaf(t, c.rx, sx);
    const float py = fmaf(t, c.ry, sy);
    const float pz = fmaf(t, c.rz, sz);
    const float fx = floorf(px), fy = floorf(py), fz = floorf(pz);
    const int ix = (int)fx, iy = (int)fy, iz = (int)fz;
    const float wx = px - fx, wy = py - fy, wz = pz - fz;

    const unsigned base = (unsigned)iz * 66048u + (unsigned)iy * 258u + (unsigned)(ix + 1);
    const __half2 q00 = vhp[base];
    const __half2 q01 = vhp[base + 66048u];
    const __half2 q10 = vhp[base + 258u];
    const __half2 q11 = vhp[base + 66306u];

    const float wx0 = 1.0f - wx, wy0 = 1.0f - wy, wz0 = 1.0f - wz;
    const float a00 = __low2float(q00) * wx0 + __high2float(q00) * wx;
    const float a01 = __low2float(q01) * wx0 + __high2float(q01) * wx;
    const float a10 = __low2float(q10) * wx0 + __high2float(q10) * wx;
    const float a11 = __low2float(q11) * wx0 + __high2float(q11) * wx;
    return (a00 * wz0 + a01 * wz) * wy0 + (a10 * wz0 + a11 * wz) * wy;
}

// Boundary sample: masks folded into weights, clamped addresses.
__device__ __forceinline__ float tri_slow(const __half2* __restrict__ vhp,
                                          float sx, float sy, float sz,
                                          const RayCfg& c, float t) {
    const float px = fmaf(t, c.rx, sx);
    const float py = fmaf(t, c.ry, sy);
    const float pz = fmaf(t, c.rz, sz);
    const float fx = floorf(px), fy = floorf(py), fz = floorf(pz);
    const int ix = (int)fx, iy = (int)fy, iz = (int)fz;
    const float wx = px - fx, wy = py - fy, wz = pz - fz;

    const float mx0 = ((unsigned)ix       < 256u) ? 1.0f : 0.0f;
    const float mx1 = ((unsigned)(ix + 1) < 256u) ? 1.0f : 0.0f;
    const float my0 = ((unsigned)iy       < 256u) ? 1.0f : 0.0f;
    const float my1 = ((unsigned)(iy + 1) < 256u) ? 1.0f : 0.0f;
    const float mz0 = ((unsigned)iz       < 256u) ? 1.0f : 0.0f;
    const float mz1 = ((unsigned)(iz + 1) < 256u) ? 1.0f : 0.0f;

    const int i  = min(max(ix + 1, 0), 257);
    const int y0 = min(max(iy,     0), 255);
    const int y1 = min(max(iy + 1, 0), 255);
    const int z0 = min(max(iz,     0), 255);
    const int z1 = min(max(iz + 1, 0), 255);

    const unsigned zt0 = (unsigned)z0 * 66048u;
    const unsigned zt1 = (unsigned)z1 * 66048u;
    const unsigned yt0 = (unsigned)y0 * 258u;
    const unsigned yt1 = (unsigned)y1 * 258u;

    const __half2 q00 = vhp[zt0 + yt0 + i];
    const __half2 q01 = vhp[zt1 + yt0 + i];
    const __half2 q10 = vhp[zt0 + yt1 + i];
    const __half2 q11 = vhp[zt1 + yt1 + i];

    const float wx0 = (1.0f - wx) * mx0, wx1 = wx * mx1;
    const float wy0 = (1.0f - wy) * my0, wy1 = wy * my1;
    const float wz0 = (1.0f - wz) * mz0, wz1 = wz * mz1;

    const float a00 = __low2float(q00) * wx0 + __high2float(q00) * wx1;
    const float a01 = __low2float(q01) * wx0 + __high2float(q01) * wx1;
    const float a10 = __low2float(q10) * wx0 + __high2float(q10) * wx1;
    const float a11 = __low2float(q11) * wx0 + __high2float(q11) * wx1;
    return (a00 * wz0 + a01 * wz1) * wy0 + (a10 * wz0 + a11 * wz1) * wy1;
}

// Grid = 4096 blocks = (1024 tiles) x (4 k-quarters). Byte-identical to r13.
__global__ __launch_bounds__(256, 8) void drr_main_pk3(const __half2* __restrict__ vhp,
                                                       const float* __restrict__ batch,
                                                       float* __restrict__ raw) {
    const int tid  = threadIdx.x;
    const int lane = tid & 63;
    const int seg  = tid >> 6;            // 0..3

    const int kq   = blockIdx.x & 3;      // k-quarter
    const int tile = blockIdx.x >> 2;     // 0..1023
    const int b    = tile >> 9;
    const int ti   = tile & 511;
    const int u    = ((ti & 15) << 4) + (lane & 15);
    const int v0   = ((ti >> 4) << 3) + ((lane >> 4) << 1);

    float sx, sy, sz;
    RayCfg A, B;
    ray_setup2(batch, b, u, v0, sx, sy, sz, A, B);

    const int klo = min(A.k_lo, B.k_lo);
    const int khi = max(A.k_hi, B.k_hi);
    const int slo = max(A.s_lo, B.s_lo);
    const int shi = min(A.s_hi, B.s_hi);

    const float tstep = 1.0f / 255.0f;
    float sA = 0.0f, sB = 0.0f;
    for (int k = klo + (kq << 2) + seg; k <= khi; k += 16) {
        const float t = (float)k * tstep;
        if (k >= slo && k <= shi) {
            sA += tri_fast(vhp, sx, sy, sz, A, t);
            sB += tri_fast(vhp, sx, sy, sz, B, t);
        } else {
            sA += tri_slow(vhp, sx, sy, sz, A, t);
            sB += tri_slow(vhp, sx, sy, sz, B, t);
        }
    }

    __shared__ float pA[4][64], pB[4][64];
    pA[seg][lane] = sA;
    pB[seg][lane] = sB;
    __syncthreads();

    if (tid < 64) {
        const float tA = pA[0][lane] + pA[1][lane] + pA[2][lane] + pA[3][lane];
        const float tB = pB[0][lane] + pB[1][lane] + pB[2][lane] + pB[3][lane];
        if (tA != 0.0f)
            atomicAdd(&raw[(b << 16) + (v0 << 8) + u],       tA * (A.length * (1.0f / 256.0f)));
        if (tB != 0.0f)
            atomicAdd(&raw[(b << 16) + ((v0 + 1) << 8) + u], tB * (B.length * (1.0f / 256.0f)));
    }
}

// Per-block min/max partials, PLAIN stores (no contended atomics).
// 512 blocks x 256 px; partial pair j = block j. part[2j]=min, part[2j+1]=max.
__global__ __launch_bounds__(256) void drr_minmax(const float* __restrict__ raw,
                                                  float* __restrict__ part) {
    __shared__ float smn[4], smx[4];
    const int gid = blockIdx.x * 256 + threadIdx.x;
    const float x = raw[gid];
    float mn = x, mx = x;
    #pragma unroll
    for (int off = 32; off >= 1; off >>= 1) {
        mn = fminf(mn, __shfl_xor(mn, off));
        mx = fmaxf(mx, __shfl_xor(mx, off));
    }
    if ((threadIdx.x & 63) == 0) {
        smn[threadIdx.x >> 6] = mn;
        smx[threadIdx.x >> 6] = mx;
    }
    __syncthreads();
    if (threadIdx.x == 0) {
        part[2 * blockIdx.x + 0] = fminf(fminf(smn[0], smn[1]), fminf(smn[2], smn[3]));
        part[2 * blockIdx.x + 1] = fmaxf(fmaxf(smx[0], smx[1]), fmaxf(smx[2], smx[3]));
    }
}

// Each block re-reduces its image's 256 partial pairs (L2-hot), then
// normalizes its 256 pixels.
__global__ __launch_bounds__(256) void drr_norm(float* __restrict__ img,
                                                const float* __restrict__ part) {
    __shared__ float smn[4], smx[4], fmn, fmx;
    const int b = blockIdx.x >> 8;          // image index
    // thread t reads partial pair (b*256 + t)
    const int pi = (b << 8) + threadIdx.x;
    float mn = part[2 * pi + 0];
    float mx = part[2 * pi + 1];
    #pragma unroll
    for (int off = 32; off >= 1; off >>= 1) {
        mn = fminf(mn, __shfl_xor(mn, off));
        mx = fmaxf(mx, __shfl_xor(mx, off));
    }
    if ((threadIdx.x & 63) == 0) {
        smn[threadIdx.x >> 6] = mn;
        smx[threadIdx.x >> 6] = mx;
    }
    __syncthreads();
    if (threadIdx.x == 0) {
        fmn = fminf(fminf(smn[0], smn[1]), fminf(smn[2], smn[3]));
        fmx = fmaxf(fmaxf(smx[0], smx[1]), fmaxf(smx[2], smx[3]));
    }
    __syncthreads();

    const int gid = blockIdx.x * 256 + threadIdx.x;
    const float inv = 1.0f / (fmx - fmn);
    img[gid] = 1.0f - (img[gid] - fmn) * inv;
}

// ---------------- fallback (ws too small for pair array): f32 path ---------
__global__ __launch_bounds__(256) void drr_transpose(const float* __restrict__ vol,
                                                     float* __restrict__ volt) {
    __shared__ float tile[64][65];
    const int bid  = blockIdx.x;
    const int y    = bid >> 4;
    const int t4   = bid & 15;
    const int x0   = (t4 & 3) << 6;
    const int z0   = (t4 >> 2) << 6;
    const int lane = threadIdx.x & 63;
    const int row4 = threadIdx.x >> 6;

    #pragma unroll
    for (int i = 0; i < 16; ++i) {
        const int xr = (i << 2) + row4;
        tile[xr][lane] = vol[((x0 + xr) << 16) | (y << 8) | (z0 + lane)];
    }
    __syncthreads();
    #pragma unroll
    for (int i = 0; i < 16; ++i) {
        const int zr = (i << 2) + row4;
        volt[((z0 + zr) << 16) | (y << 8) | (x0 + lane)] = tile[lane][zr];
    }
}

__device__ __forceinline__ float tri_sample_f32(const float* __restrict__ vol,
                                                float sx, float sy, float sz,
                                                const RayCfg& c, float t) {
    const float px = fmaf(t, c.rx, sx);
    const float py = fmaf(t, c.ry, sy);
    const float pz = fmaf(t, c.rz, sz);
    const float fx = floorf(px), fy = floorf(py), fz = floorf(pz);
    const int ix = (int)fx, iy = (int)fy, iz = (int)fz;
    const float wx = px - fx, wy = py - fy, wz = pz - fz;
    const float mx0 = ((unsigned)ix       < 256u) ? 1.0f : 0.0f;
    const float mx1 = ((unsigned)(ix + 1) < 256u) ? 1.0f : 0.0f;
    const float my0 = ((unsigned)iy       < 256u) ? 1.0f : 0.0f;
    const float my1 = ((unsigned)(iy + 1) < 256u) ? 1.0f : 0.0f;
    const float mz0 = ((unsigned)iz       < 256u) ? 1.0f : 0.0f;
    const float mz1 = ((unsigned)(iz + 1) < 256u) ? 1.0f : 0.0f;
    const unsigned X0 = (unsigned)ix & 255u, X1 = (unsigned)(ix + 1) & 255u;
    const unsigned Y0 = ((unsigned)iy & 255u) << 8, Y1 = ((unsigned)(iy + 1) & 255u) << 8;
    const unsigned Z0 = ((unsigned)iz & 255u) << 16, Z1 = ((unsigned)(iz + 1) & 255u) << 16;
    const float v000 = vol[Z0 | Y0 | X0];
    const float v001 = vol[Z1 | Y0 | X0];
    const float v010 = vol[Z0 | Y1 | X0];
    const float v011 = vol[Z1 | Y1 | X0];
    const float v100 = vol[Z0 | Y0 | X1];
    const float v101 = vol[Z1 | Y0 | X1];
    const float v110 = vol[Z0 | Y1 | X1];
    const float v111 = vol[Z1 | Y1 | X1];
    const float wx0 = (1.0f - wx) * mx0, wx1 = wx * mx1;
    const float wy0 = (1.0f - wy) * my0, wy1 = wy * my1;
    const float wz0 = (1.0f - wz) * mz0, wz1 = wz * mz1;
    const float c00 = v000 * wz0 + v001 * wz1;
    const float c01 = v010 * wz0 + v011 * wz1;
    const float c10 = v100 * wz0 + v101 * wz1;
    const float c11 = v110 * wz0 + v111 * wz1;
    return (c00 * wy0 + c01 * wy1) * wx0 + (c10 * wy0 + c11 * wy1) * wx1;
}

__global__ __launch_bounds__(256, 4) void drr_main_f32(const float* __restrict__ volt,
                                                       const float* __restrict__ batch,
                                                       float* __restrict__ raw,
                                                       unsigned* __restrict__ mm) {
    const int tid  = threadIdx.x;
    const int lane = tid & 63;
    const int seg  = tid >> 6;
    const int tile = blockIdx.x;
    const int b    = tile >> 10;
    const int ti   = tile & 1023;
    const int u    = ((ti & 15) << 4) + (lane & 15);
    const int v    = ((ti >> 4) << 2) + (lane >> 4);

    float sx, sy, sz;
    RayCfg A, B;
    ray_setup2(batch, b, u, v, sx, sy, sz, A, B);  // use A only

    const float tstep = 1.0f / 255.0f;
    float sum = 0.0f;
    for (int k = A.k_lo + seg; k <= A.k_hi; k += 4)
        sum += tri_sample_f32(volt, sx, sy, sz, A, (float)k * tstep);

    __shared__ float part[4][64];
    part[seg][lane] = sum;
    __syncthreads();

    if (tid < 64) {
        const float s = part[0][lane] + part[1][lane] + part[2][lane] + part[3][lane];
        const float rawv = s * (A.length * (1.0f / 256.0f));
        raw[(b << 16) + (v << 8) + u] = rawv;
        float mn = rawv, mx = rawv;
        #pragma unroll
        for (int off = 32; off >= 1; off >>= 1) {
            mn = fminf(mn, __shfl_xor(mn, off));
            mx = fmaxf(mx, __shfl_xor(mx, off));
        }
        if (lane == 0) {
            atomicMin(&mm[2 * b + 0], __float_as_uint(mn));
            atomicMax(&mm[2 * b + 1], __float_as_uint(mx));
        }
    }
}

__global__ __launch_bounds__(256) void drr_norm_mm(float* __restrict__ img,
                                                   const unsigned* __restrict__ mm) {
    const int gid = blockIdx.x * 256 + threadIdx.x;
    const int b   = gid >> 16;
    const float mn  = __uint_as_float(mm[2 * b + 0]);
    const float mx  = __uint_as_float(mm[2 * b + 1]);
    const float inv = 1.0f / (mx - mn);
    img[gid] = 1.0f - (img[gid] - mn) * inv;
}

extern "C" void kernel_launch(void* const* d_in, const int* in_sizes, int n_in,
                              void* d_out, int out_size, void* d_ws, size_t ws_size,
                              hipStream_t stream) {
    const float* vol   = (const float*)d_in[0];
    const float* batch = (const float*)d_in[1];
    float* out         = (float*)d_out;

    if (ws_size >= (size_t)PAIR_BYTES + 4096) {
        __half2* vhp  = (__half2*)d_ws;
        float*   part = (float*)((char*)d_ws + PAIR_BYTES);  // 512 pairs
        drr_pack<<<4096, 256, 0, stream>>>(vol, vhp, out);
        drr_main_pk3<<<4096, 256, 0, stream>>>(vhp, batch, out);
        drr_minmax<<<512, 256, 0, stream>>>(out, part);
        drr_norm<<<512, 256, 0, stream>>>(out, part);
    } else {
        float*    volt = (float*)d_ws;
        unsigned* mm   = (unsigned*)((char*)d_ws + VOL_BYTES);
        drr_init_mm<<<1, 64, 0, stream>>>(mm);
        drr_transpose<<<4096, 256, 0, stream>>>(vol, volt);
        drr_main_f32<<<2048, 256, 0, stream>>>(volt, batch, out, mm);
        drr_norm_mm<<<512, 256, 0, stream>>>(out, mm);
    }
}

// Round 15
// 80.121 us; speedup vs baseline: 1.6104x; 1.0388x over previous
//
#include <hip/hip_runtime.h>
#include <hip/hip_fp16.h>

// DRR ray-casting for MI355X — round 15.
// r14 confirmed the atomic-contention theory (129 -> 83.2 us). Main (50.2 us)
// is near the gather line-service floor but VALUBusy=41% says VALU co-limits.
// r15 single change: x-lerp via v_dot2_f32_f16 (__builtin_amdgcn_fdot2) in
// tri_fast/tri_slow — replaces 8 cvt + 8 mul/fma per sample with 1 cvt_pkrtz
// + 4 dot2. RTZ weight bias is common-mode and cancels in normalization.

static __device__ __constant__ float kPX     = 1.6875f;
static __device__ __constant__ float kPIERCE = 216.0f;
static __device__ __constant__ float kSAD    = 742.5f;
static __device__ __constant__ float kDAD    = 517.15f;

#define VOL_BYTES   (256u * 256u * 256u * 4u)
#define PAIR_R      258u
#define PAIR_ELEMS  (256u * 256u * PAIR_R)          // half2 elements
#define PAIR_BYTES  (PAIR_ELEMS * 4u)

typedef __fp16 half2_raw __attribute__((ext_vector_type(2)));

__global__ void drr_init_mm(unsigned* mm) {
    int i = threadIdx.x;
    if (i < 4) mm[i] = (i & 1) ? 0u : 0x7F800000u;  // max<-0, min<-+inf
}

// ---------------- pack: vol[x][y][z] -> vhp[z][y][i] = (v[i-1], v[i]) fp16 ---
// r10-proven body. Also zeroes raw (for main's atomic partial sums).
__global__ __launch_bounds__(256) void drr_pack(const float* __restrict__ vol,
                                                __half2* __restrict__ vhp,
                                                float* __restrict__ raw) {
    const int bid = blockIdx.x;
    if (threadIdx.x < 32)
        raw[(bid << 5) + threadIdx.x] = 0.0f;

    __shared__ float tile[65][65];
    const int y    = bid >> 4;
    const int t4   = bid & 15;
    const int x0   = (t4 & 3) << 6;
    const int z0   = (t4 >> 2) << 6;

    const int rr = threadIdx.x >> 4;   // 0..15 row within pass
    const int cc = threadIdx.x & 15;   // 0..15 float4 column
    #pragma unroll
    for (int base = 0; base < 80; base += 16) {
        const int r = base + rr;
        if (r < 65) {
            const int x = x0 - 1 + r;
            float4 f = make_float4(0.0f, 0.0f, 0.0f, 0.0f);
            if (x >= 0)
                f = *(const float4*)&vol[(x << 16) | (y << 8) | (z0 + (cc << 2))];
            tile[r][(cc << 2) + 0] = f.x;
            tile[r][(cc << 2) + 1] = f.y;
            tile[r][(cc << 2) + 2] = f.z;
            tile[r][(cc << 2) + 3] = f.w;
        }
    }
    __syncthreads();

    const int lane = threadIdx.x & 63;
    const int row4 = threadIdx.x >> 6;  // 0..3
    for (int r = row4; r < 64; r += 4) {
        const int z = z0 + r;
        const unsigned base = (unsigned)((z << 8) | y) * PAIR_R;
        vhp[base + x0 + lane] =
            __halves2half2(__float2half(tile[lane][r]), __float2half(tile[lane + 1][r]));
    }
    if ((t4 & 3) == 3) {
        for (int r = row4; r < 64; r += 4) {
            const int z = z0 + r;
            const unsigned base = (unsigned)((z << 8) | y) * PAIR_R;
            if (lane == 0) {
                vhp[base + 256] = __halves2half2(__float2half(tile[64][r]), __float2half(0.0f));
                vhp[base + 257] = __halves2half2(__float2half(0.0f), __float2half(0.0f));
            }
        }
    }
}

// Per-dimension slab: tighten [tlo, thi] to where s + t*r is in [lo, hi].
__device__ __forceinline__ void slab(float s, float r, float lo, float hi,
                                     float& tlo, float& thi) {
    if (fabsf(r) > 1e-8f) {
        const float inv = 1.0f / r;
        const float ta  = (lo - s) * inv;
        const float tb  = (hi - s) * inv;
        tlo = fmaxf(tlo, fminf(ta, tb));
        thi = fminf(thi, fmaxf(ta, tb));
    } else if (s < lo || s > hi) {
        tlo = 2.0f; thi = -1.0f;  // empty
    }
}

struct RayCfg {
    float rx, ry, rz, length;
    int k_lo, k_hi;   // loose window (outside: exactly zero via masks)
    int s_lo, s_hi;   // strict window (inside: all masks 1, no clamps)
};

__device__ __forceinline__ void cfg_windows(float sx, float sy, float sz, RayCfg& c) {
    float tlo = 0.0f, thi = 1.0f;
    slab(sx, c.rx, -1.02f, 256.02f, tlo, thi);
    slab(sy, c.ry, -1.02f, 256.02f, tlo, thi);
    slab(sz, c.rz, -1.02f, 256.02f, tlo, thi);
    c.k_lo = 0; c.k_hi = -1;
    if (thi >= tlo) {
        c.k_lo = max(0,   (int)ceilf(tlo * 255.0f - 1e-3f));
        c.k_hi = min(255, (int)floorf(thi * 255.0f + 1e-3f));
    }
    float slo = 0.0f, shi = 1.0f;
    slab(sx, c.rx, 0.01f, 254.99f, slo, shi);
    slab(sy, c.ry, 0.01f, 254.99f, slo, shi);
    slab(sz, c.rz, 0.01f, 254.99f, slo, shi);
    c.s_lo = 1; c.s_hi = -1;
    if (shi >= slo) {
        c.s_lo = (int)ceilf(slo * 255.0f + 1e-3f);
        c.s_hi = (int)floorf(shi * 255.0f - 1e-3f);
    }
}

// Shared pose math; A = pixel (u, v0), B = pixel (u, v0+1).
__device__ __forceinline__ void ray_setup2(const float* __restrict__ batch,
                                           int b, int u, int v0,
                                           float& sx, float& sy, float& sz,
                                           RayCfg& A, RayCfg& B) {
    const float a  = batch[b * 6 + 0];
    const float be = batch[b * 6 + 1];
    const float g  = batch[b * 6 + 2];
    const float tx = batch[b * 6 + 3];
    const float ty = batch[b * 6 + 4];
    const float tz = batch[b * 6 + 5];

    float sa, ca, sb, cb, sg, cg;
    sincosf(a, &sa, &ca);
    sincosf(be, &sb, &cb);
    sincosf(g, &sg, &cg);

    const float R00 = ca * cb;
    const float R01 = ca * sb * sg - sa * cg;
    const float R02 = sa * sg + ca * sb * cg;
    const float R10 = sa * cb;
    const float R11 = ca * cg + sa * sb * sg;
    const float R12 = sa * sb * cg - ca * sg;
    const float R20 = -sb;
    const float R21 = cb * sg;
    const float R22 = cb * cg;

    sx = 128.0f + tx + kSAD * R02;
    sy = 128.0f + ty + kSAD * R12;
    sz = 128.0f + tz + kSAD * R22;

    const float uu = u * kPX - kPIERCE;
    const float vv = v0 * kPX - kPIERCE;
    A.rx = uu * R00 + vv * R01 - (kSAD + kDAD) * R02;
    A.ry = uu * R10 + vv * R11 - (kSAD + kDAD) * R12;
    A.rz = uu * R20 + vv * R21 - (kSAD + kDAD) * R22;
    B.rx = A.rx + kPX * R01;
    B.ry = A.ry + kPX * R11;
    B.rz = A.rz + kPX * R21;
    A.length = sqrtf(A.rx * A.rx + A.ry * A.ry + A.rz * A.rz);
    B.length = sqrtf(B.rx * B.rx + B.ry * B.ry + B.rz * B.rz);
    cfg_windows(sx, sy, sz, A);
    cfg_windows(sx, sy, sz, B);
}

// x-lerp via v_dot2_f32_f16: lo*w0 + hi*w1 in one instruction.
__device__ __forceinline__ float xdot(__half2 q, half2_raw w) {
    return __builtin_amdgcn_fdot2(__builtin_bit_cast(half2_raw, q), w, 0.0f, false);
}

// Interior sample: all 8 corners in-bounds, no masks/clamps.
__device__ __forceinline__ float tri_fast(const __half2* __restrict__ vhp,
                                          float sx, float sy, float sz,
                                          const RayCfg& c, float t) {
    const float px = fmaf(t, c.rx, sx);
    const float py = fmaf(t, c.ry, sy);
    const float pz = fmaf(t, c.rz, sz);
    const float fx = floorf(px), fy = floorf(py), fz = floorf(pz);
    const int ix = (int)fx, iy = (int)fy, iz = (int)fz;
    const float wx = px - fx, wy = py - fy, wz = pz - fz;

    const unsigned base = (unsigned)iz * 66048u + (unsigned)iy * 258u + (unsigned)(ix + 1);
    const __half2 q00 = vhp[base];
    const __half2 q01 = vhp[base + 66048u];
    const __half2 q10 = vhp[base + 258u];
    const __half2 q11 = vhp[base + 66306u];

    const half2_raw wxh = __builtin_amdgcn_cvt_pkrtz(1.0f - wx, wx);
    const float a00 = xdot(q00, wxh);
    const float a01 = xdot(q01, wxh);
    const float a10 = xdot(q10, wxh);
    const float a11 = xdot(q11, wxh);

    const float wy0 = 1.0f - wy, wz0 = 1.0f - wz;
    return (a00 * wz0 + a01 * wz) * wy0 + (a10 * wz0 + a11 * wz) * wy;
}

// Boundary sample: masks folded into weights, clamped addresses.
__device__ __forceinline__ float tri_slow(const __half2* __restrict__ vhp,
                                          float sx, float sy, float sz,
                                          const RayCfg& c, float t) {
    const float px = fmaf(t, c.rx, sx);
    const float py = fmaf(t, c.ry, sy);
    const float pz = fmaf(t, c.rz, sz);
    const float fx = floorf(px), fy = floorf(py), fz = floorf(pz);
    const int ix = (int)fx, iy = (int)fy, iz = (int)fz;
    const float wx = px - fx, wy = py - fy, wz = pz - fz;

    const float mx0 = ((unsigned)ix       < 256u) ? 1.0f : 0.0f;
    const float mx1 = ((unsigned)(ix + 1) < 256u) ? 1.0f : 0.0f;
    const float my0 = ((unsigned)iy       < 256u) ? 1.0f : 0.0f;
    const float my1 = ((unsigned)(iy + 1) < 256u) ? 1.0f : 0.0f;
    const float mz0 = ((unsigned)iz       < 256u) ? 1.0f : 0.0f;
    const float mz1 = ((unsigned)(iz + 1) < 256u) ? 1.0f : 0.0f;

    const int i  = min(max(ix + 1, 0), 257);
    const int y0 = min(max(iy,     0), 255);
    const int y1 = min(max(iy + 1, 0), 255);
    const int z0 = min(max(iz,     0), 255);
    const int z1 = min(max(iz + 1, 0), 255);

    const unsigned zt0 = (unsigned)z0 * 66048u;
    const unsigned zt1 = (unsigned)z1 * 66048u;
    const unsigned yt0 = (unsigned)y0 * 258u;
    const unsigned yt1 = (unsigned)y1 * 258u;

    const __half2 q00 = vhp[zt0 + yt0 + i];
    const __half2 q01 = vhp[zt1 + yt0 + i];
    const __half2 q10 = vhp[zt0 + yt1 + i];
    const __half2 q11 = vhp[zt1 + yt1 + i];

    const half2_raw wxh = __builtin_amdgcn_cvt_pkrtz((1.0f - wx) * mx0, wx * mx1);
    const float a00 = xdot(q00, wxh);
    const float a01 = xdot(q01, wxh);
    const float a10 = xdot(q10, wxh);
    const float a11 = xdot(q11, wxh);

    const float wy0 = (1.0f - wy) * my0, wy1 = wy * my1;
    const float wz0 = (1.0f - wz) * mz0, wz1 = wz * mz1;
    return (a00 * wz0 + a01 * wz1) * wy0 + (a10 * wz0 + a11 * wz1) * wy1;
}

// Grid = 4096 blocks = (1024 tiles) x (4 k-quarters). Structure identical to
// r13/r14 (proven 50.4 us).
__global__ __launch_bounds__(256, 8) void drr_main_pk3(const __half2* __restrict__ vhp,
                                                       const float* __restrict__ batch,
                                                       float* __restrict__ raw) {
    const int tid  = threadIdx.x;
    const int lane = tid & 63;
    const int seg  = tid >> 6;            // 0..3

    const int kq   = blockIdx.x & 3;      // k-quarter
    const int tile = blockIdx.x >> 2;     // 0..1023
    const int b    = tile >> 9;
    const int ti   = tile & 511;
    const int u    = ((ti & 15) << 4) + (lane & 15);
    const int v0   = ((ti >> 4) << 3) + ((lane >> 4) << 1);

    float sx, sy, sz;
    RayCfg A, B;
    ray_setup2(batch, b, u, v0, sx, sy, sz, A, B);

    const int klo = min(A.k_lo, B.k_lo);
    const int khi = max(A.k_hi, B.k_hi);
    const int slo = max(A.s_lo, B.s_lo);
    const int shi = min(A.s_hi, B.s_hi);

    const float tstep = 1.0f / 255.0f;
    float sA = 0.0f, sB = 0.0f;
    for (int k = klo + (kq << 2) + seg; k <= khi; k += 16) {
        const float t = (float)k * tstep;
        if (k >= slo && k <= shi) {
            sA += tri_fast(vhp, sx, sy, sz, A, t);
            sB += tri_fast(vhp, sx, sy, sz, B, t);
        } else {
            sA += tri_slow(vhp, sx, sy, sz, A, t);
            sB += tri_slow(vhp, sx, sy, sz, B, t);
        }
    }

    __shared__ float pA[4][64], pB[4][64];
    pA[seg][lane] = sA;
    pB[seg][lane] = sB;
    __syncthreads();

    if (tid < 64) {
        const float tA = pA[0][lane] + pA[1][lane] + pA[2][lane] + pA[3][lane];
        const float tB = pB[0][lane] + pB[1][lane] + pB[2][lane] + pB[3][lane];
        if (tA != 0.0f)
            atomicAdd(&raw[(b << 16) + (v0 << 8) + u],       tA * (A.length * (1.0f / 256.0f)));
        if (tB != 0.0f)
            atomicAdd(&raw[(b << 16) + ((v0 + 1) << 8) + u], tB * (B.length * (1.0f / 256.0f)));
    }
}

// Per-block min/max partials, PLAIN stores (no contended atomics).
__global__ __launch_bounds__(256) void drr_minmax(const float* __restrict__ raw,
                                                  float* __restrict__ part) {
    __shared__ float smn[4], smx[4];
    const int gid = blockIdx.x * 256 + threadIdx.x;
    const float x = raw[gid];
    float mn = x, mx = x;
    #pragma unroll
    for (int off = 32; off >= 1; off >>= 1) {
        mn = fminf(mn, __shfl_xor(mn, off));
        mx = fmaxf(mx, __shfl_xor(mx, off));
    }
    if ((threadIdx.x & 63) == 0) {
        smn[threadIdx.x >> 6] = mn;
        smx[threadIdx.x >> 6] = mx;
    }
    __syncthreads();
    if (threadIdx.x == 0) {
        part[2 * blockIdx.x + 0] = fminf(fminf(smn[0], smn[1]), fminf(smn[2], smn[3]));
        part[2 * blockIdx.x + 1] = fmaxf(fmaxf(smx[0], smx[1]), fmaxf(smx[2], smx[3]));
    }
}

// Each block re-reduces its image's 256 partial pairs, then normalizes.
__global__ __launch_bounds__(256) void drr_norm(float* __restrict__ img,
                                                const float* __restrict__ part) {
    __shared__ float smn[4], smx[4], fmn, fmx;
    const int b = blockIdx.x >> 8;          // image index
    const int pi = (b << 8) + threadIdx.x;
    float mn = part[2 * pi + 0];
    float mx = part[2 * pi + 1];
    #pragma unroll
    for (int off = 32; off >= 1; off >>= 1) {
        mn = fminf(mn, __shfl_xor(mn, off));
        mx = fmaxf(mx, __shfl_xor(mx, off));
    }
    if ((threadIdx.x & 63) == 0) {
        smn[threadIdx.x >> 6] = mn;
        smx[threadIdx.x >> 6] = mx;
    }
    __syncthreads();
    if (threadIdx.x == 0) {
        fmn = fminf(fminf(smn[0], smn[1]), fminf(smn[2], smn[3]));
        fmx = fmaxf(fmaxf(smx[0], smx[1]), fmaxf(smx[2], smx[3]));
    }
    __syncthreads();

    const int gid = blockIdx.x * 256 + threadIdx.x;
    const float inv = 1.0f / (fmx - fmn);
    img[gid] = 1.0f - (img[gid] - fmn) * inv;
}

// ---------------- fallback (ws too small for pair array): f32 path ---------
__global__ __launch_bounds__(256) void drr_transpose(const float* __restrict__ vol,
                                                     float* __restrict__ volt) {
    __shared__ float tile[64][65];
    const int bid  = blockIdx.x;
    const int y    = bid >> 4;
    const int t4   = bid & 15;
    const int x0   = (t4 & 3) << 6;
    const int z0   = (t4 >> 2) << 6;
    const int lane = threadIdx.x & 63;
    const int row4 = threadIdx.x >> 6;

    #pragma unroll
    for (int i = 0; i < 16; ++i) {
        const int xr = (i << 2) + row4;
        tile[xr][lane] = vol[((x0 + xr) << 16) | (y << 8) | (z0 + lane)];
    }
    __syncthreads();
    #pragma unroll
    for (int i = 0; i < 16; ++i) {
        const int zr = (i << 2) + row4;
        volt[((z0 + zr) << 16) | (y << 8) | (x0 + lane)] = tile[lane][zr];
    }
}

__device__ __forceinline__ float tri_sample_f32(const float* __restrict__ vol,
                                                float sx, float sy, float sz,
                                                const RayCfg& c, float t) {
    const float px = fmaf(t, c.rx, sx);
    const float py = fmaf(t, c.ry, sy);
    const float pz = fmaf(t, c.rz, sz);
    const float fx = floorf(px), fy = floorf(py), fz = floorf(pz);
    const int ix = (int)fx, iy = (int)fy, iz = (int)fz;
    const float wx = px - fx, wy = py - fy, wz = pz - fz;
    const float mx0 = ((unsigned)ix       < 256u) ? 1.0f : 0.0f;
    const float mx1 = ((unsigned)(ix + 1) < 256u) ? 1.0f : 0.0f;
    const float my0 = ((unsigned)iy       < 256u) ? 1.0f : 0.0f;
    const float my1 = ((unsigned)(iy + 1) < 256u) ? 1.0f : 0.0f;
    const float mz0 = ((unsigned)iz       < 256u) ? 1.0f : 0.0f;
    const float mz1 = ((unsigned)(iz + 1) < 256u) ? 1.0f : 0.0f;
    const unsigned X0 = (unsigned)ix & 255u, X1 = (unsigned)(ix + 1) & 255u;
    const unsigned Y0 = ((unsigned)iy & 255u) << 8, Y1 = ((unsigned)(iy + 1) & 255u) << 8;
    const unsigned Z0 = ((unsigned)iz & 255u) << 16, Z1 = ((unsigned)(iz + 1) & 255u) << 16;
    const float v000 = vol[Z0 | Y0 | X0];
    const float v001 = vol[Z1 | Y0 | X0];
    const float v010 = vol[Z0 | Y1 | X0];
    const float v011 = vol[Z1 | Y1 | X0];
    const float v100 = vol[Z0 | Y0 | X1];
    const float v101 = vol[Z1 | Y0 | X1];
    const float v110 = vol[Z0 | Y1 | X1];
    const float v111 = vol[Z1 | Y1 | X1];
    const float wx0 = (1.0f - wx) * mx0, wx1 = wx * mx1;
    const float wy0 = (1.0f - wy) * my0, wy1 = wy * my1;
    const float wz0 = (1.0f - wz) * mz0, wz1 = wz * mz1;
    const float c00 = v000 * wz0 + v001 * wz1;
    const float c01 = v010 * wz0 + v011 * wz1;
    const float c10 = v100 * wz0 + v101 * wz1;
    const float c11 = v110 * wz0 + v111 * wz1;
    return (c00 * wy0 + c01 * wy1) * wx0 + (c10 * wy0 + c11 * wy1) * wx1;
}

__global__ __launch_bounds__(256, 4) void drr_main_f32(const float* __restrict__ volt,
                                                       const float* __restrict__ batch,
                                                       float* __restrict__ raw,
                                                       unsigned* __restrict__ mm) {
    const int tid  = threadIdx.x;
    const int lane = tid & 63;
    const int seg  = tid >> 6;
    const int tile = blockIdx.x;
    const int b    = tile >> 10;
    const int ti   = tile & 1023;
    const int u    = ((ti & 15) << 4) + (lane & 15);
    const int v    = ((ti >> 4) << 2) + (lane >> 4);

    float sx, sy, sz;
    RayCfg A, B;
    ray_setup2(batch, b, u, v, sx, sy, sz, A, B);  // use A only

    const float tstep = 1.0f / 255.0f;
    float sum = 0.0f;
    for (int k = A.k_lo + seg; k <= A.k_hi; k += 4)
        sum += tri_sample_f32(volt, sx, sy, sz, A, (float)k * tstep);

    __shared__ float part[4][64];
    part[seg][lane] = sum;
    __syncthreads();

    if (tid < 64) {
        const float s = part[0][lane] + part[1][lane] + part[2][lane] + part[3][lane];
        const float rawv = s * (A.length * (1.0f / 256.0f));
        raw[(b << 16) + (v << 8) + u] = rawv;
        float mn = rawv, mx = rawv;
        #pragma unroll
        for (int off = 32; off >= 1; off >>= 1) {
            mn = fminf(mn, __shfl_xor(mn, off));
            mx = fmaxf(mx, __shfl_xor(mx, off));
        }
        if (lane == 0) {
            atomicMin(&mm[2 * b + 0], __float_as_uint(mn));
            atomicMax(&mm[2 * b + 1], __float_as_uint(mx));
        }
    }
}

__global__ __launch_bounds__(256) void drr_norm_mm(float* __restrict__ img,
                                                   const unsigned* __restrict__ mm) {
    const int gid = blockIdx.x * 256 + threadIdx.x;
    const int b   = gid >> 16;
    const float mn  = __uint_as_float(mm[2 * b + 0]);
    const float mx  = __uint_as_float(mm[2 * b + 1]);
    const float inv = 1.0f / (mx - mn);
    img[gid] = 1.0f - (img[gid] - mn) * inv;
}

extern "C" void kernel_launch(void* const* d_in, const int* in_sizes, int n_in,
                              void* d_out, int out_size, void* d_ws, size_t ws_size,
                              hipStream_t stream) {
    const float* vol   = (const float*)d_in[0];
    const float* batch = (const float*)d_in[1];
    float* out         = (float*)d_out;

    if (ws_size >= (size_t)PAIR_BYTES + 4096) {
        __half2* vhp  = (__half2*)d_ws;
        float*   part = (float*)((char*)d_ws + PAIR_BYTES);  // 512 pairs
        drr_pack<<<4096, 256, 0, stream>>>(vol, vhp, out);
        drr_main_pk3<<<4096, 256, 0, stream>>>(vhp, batch, out);
        drr_minmax<<<512, 256, 0, stream>>>(out, part);
        drr_norm<<<512, 256, 0, stream>>>(out, part);
    } else {
        float*    volt = (float*)d_ws;
        unsigned* mm   = (unsigned*)((char*)d_ws + VOL_BYTES);
        drr_init_mm<<<1, 64, 0, stream>>>(mm);
        drr_transpose<<<4096, 256, 0, stream>>>(vol, volt);
        drr_main_f32<<<2048, 256, 0, stream>>>(volt, batch, out, mm);
        drr_norm_mm<<<512, 256, 0, stream>>>(out, mm);
    }
}